// Round 8
// baseline (107.126 us; speedup 1.0000x reference)
//
#include <hip/hip_runtime.h>
#include <math.h>

// Problem constants
constexpr int IMG     = 384;
constexpr int NPIX    = IMG * IMG;        // 147456
constexpr int TM1     = 10;               // T-1
constexpr int NIMG    = 80;               // B * (T-1)
constexpr int THREADS = 256;
constexpr int GPT     = 4;                // quads per thread
constexpr int GPB     = THREADS * GPT;    // 1024 quads per block
constexpr int NGRP    = NPIX / 4;         // 36864 quad slots
constexpr int NBX     = NGRP / GPB;       // 36 streamer blocks per image
constexpr int NSUM    = 12;               // 3 planes x 4 row-stripes per image
constexpr long long NMASK = (long long)NIMG * NPIX;  // 11,796,480

typedef float v4f __attribute__((ext_vector_type(4)));

// Conservative per-(plane,row) pixel-column interval [plo,phi] outside which
// the plane's f32 mask predicate is provably 0. Packed plo | phi<<10.
// 1000u (plo=1000, phi=0) == empty. Pure function of (plane, r, scalars):
// called identically by streamer and region blocks -> identical values.
__device__ __forceinline__ unsigned row_pack(int plane, int r,
    double c, double s, double x0, double y0,
    double dy, double dyl, double ox, double oy)
{
    double u0, u1, v0, v1;
    if (plane == 0)      { u0 = -5.05;    u1 = 5.05;     v0 = 0.0;    v1 = dy; }
    else if (plane == 1) { u0 = -1.155;   u1 = 1.155;    v0 = -2.695; v1 = 2.695; }
    else                 { u0 = ox - 3.1; u1 = ox + 3.1; v0 = -oy;    v1 = dyl - oy; }
    const double Yd = (double)r * 0.2 - 38.4;
    // ax(j) = mA*j + qA ; ay(j) = mB*j + qB  (exact affine forms)
    const double mA = c * 0.2;
    const double qA = c * (-38.4 - x0) + s * (Yd - y0);
    const double mB = -s * 0.2;
    const double qB = c * (Yd - y0) + s * (38.4 + x0);
    double lo = -1e9, hi = 1e9;
    bool empty = false;
    if (fabs(mA) > 1e-12) {
        const double pad = 1e-3 / fabs(mA);   // covers f32 eval error <=1e-4 m
        const double t0 = (u0 - qA) / mA, t1 = (u1 - qA) / mA;
        lo = fmax(lo, fmin(t0, t1) - pad);
        hi = fmin(hi, fmax(t0, t1) + pad);
    } else if (qA < u0 - 1e-3 || qA > u1 + 1e-3) empty = true;
    if (fabs(mB) > 1e-12) {
        const double pad = 1e-3 / fabs(mB);
        const double t0 = (v0 - qB) / mB, t1 = (v1 - qB) / mB;
        lo = fmax(lo, fmin(t0, t1) - pad);
        hi = fmin(hi, fmax(t0, t1) + pad);
    } else if (qB < v0 - 1e-3 || qB > v1 + 1e-3) empty = true;
    lo -= 1.0; hi += 1.0;                      // integer-rounding guard
    if (empty || hi < 0.0 || lo > 383.0 || lo > hi) return 1000u;
    lo = fmax(lo, 0.0); hi = fmin(hi, 383.0);
    return (unsigned)(int)floor(lo) | (((unsigned)(int)ceil(hi)) << 10);
}

// Output layout: [0..6] = 7 scalar costs, then mask_car, mask_side, mask_light

__global__ __launch_bounds__(THREADS) void cost_main(
    const float* __restrict__ loc,    // (8,11,2)
    const float* __restrict__ yaw,    // (8,11,1)
    const float* __restrict__ speed,  // (8,11,1)
    const float* __restrict__ bev,    // (8,11,8,384,384)
    float* __restrict__ out)
{
    const int img = blockIdx.y;          // 0..79
    const int b   = img / TM1;
    const int t   = img - b * TM1;       // bev time index t+1
    const int tid = threadIdx.x;

    // ---- per-image scalars (f32, identical to prior rounds) ----
    const float yaw0 = yaw[b * 11];
    const float c0 = cosf(yaw0), s0 = sinf(yaw0);
    const float rx = loc[(b * 11 + t + 1) * 2 + 0] - loc[b * 22 + 0];
    const float ry = loc[(b * 11 + t + 1) * 2 + 1] - loc[b * 22 + 1];
    const float x0 =  c0 * rx + s0 * ry;
    const float y0 = -s0 * rx + c0 * ry;
    const float yw = yaw[b * 11 + t + 1] - yaw0;
    const float c = cosf(yw), s = sinf(yw);
    const float sp  = speed[b * 11 + t + 1];
    const float dy  = 1.5f * (fmaxf(10.0f, sp) + 4.9f) + 1.0f;
    const float dyl = sp * 0.5f + 14.7f;
    const float ox  = 12.0f * c + 3.25f * s;
    const float oy  = 12.0f * s - 3.25f * c;

    // widened copies for the interval function
    const double cd = c, sd = s, x0d = x0, y0d = y0;
    const double dyd = dy, dyld = dyl, oxd = ox, oyd = oy;

    if (blockIdx.x < NBX) {
        // ============ streamer: zero-fill everything outside intervals ======
        __shared__ unsigned spk[42];         // (<=13 rows + 1 neighbor) x 3
        const int g0s = blockIdx.x * GPB;
        const int rlo = (4 * g0s + 1) / IMG;
        const int rhi = min(IMG - 1, (4 * (g0s + GPB - 1) + 4) / IMG);
        const int nent = (rhi - rlo + 2) * 3;    // rows rlo..rhi+1
        for (int idx = tid; idx < nent; idx += THREADS) {
            const int rr = rlo + idx / 3;
            const int pl = idx - (idx / 3) * 3;
            spk[idx] = (rr < IMG) ? row_pack(pl, rr, cd, sd, x0d, y0d,
                                             dyd, dyld, oxd, oyd)
                                  : 1000u;
        }
        __syncthreads();

        float* base = out + 7 + (size_t)img * NPIX;
        const v4f z4 = {0.f, 0.f, 0.f, 0.f};
        const int g0 = g0s + tid;
        #pragma unroll
        for (int it = 0; it < GPT; ++it) {
            const int g = g0 + it * THREADS;
            if (g == NGRP - 1) continue;     // leftover handled elsewhere
            const int p1   = 4 * g + 1;
            const int r    = p1 / IMG;
            const int col1 = p1 - r * IMG;   // 4k+1
            const int k    = col1 >> 2;
            const int c4   = col1 + 3;
            const int ro   = (r - rlo) * 3;
            #pragma unroll
            for (int pl = 0; pl < 3; ++pl) {
                const unsigned pk = spk[ro + pl];
                const int plo = pk & 1023, phi = (pk >> 10) & 1023;
                bool skip = (c4 >= plo) && (col1 <= phi);
                if (k == 95 && r < IMG - 1)   // straddle quad owns next row col0
                    skip = skip || ((spk[ro + 3 + pl] & 1023u) == 0u);
                if (!skip)
                    *(v4f*)(base + (size_t)pl * NMASK + p1) = z4;
            }
        }
        return;
    }

    // ============ region blocks: exact masks + gated sums inside intervals ==
    const int q     = blockIdx.x - NBX;  // 0..11
    const int plane = q >> 2;            // 0=car, 1=side, 2=light
    const int z     = q & 3;             // row stripe

    __shared__ unsigned spk2[192];       // [m][parity]: rows z+4m, z+4m+1
    for (int idx = tid; idx < 192; idx += THREADS) {
        const int m  = idx >> 1;
        const int rr = z + 4 * m + (idx & 1);
        spk2[idx] = (rr < IMG) ? row_pack(plane, rr, cd, sd, x0d, y0d,
                                          dyd, dyld, oxd, oyd)
                               : 1000u;
    }
    __syncthreads();

    const float* bp = bev + (size_t)((b * 11 + t + 1) * 8) * NPIX;
    float* op = out + 7 + (size_t)img * NPIX + (size_t)plane * NMASK;
    int chA, chB, chC;
    if (plane == 0)      { chA = 2; chB = 6; chC = -1; }
    else if (plane == 1) { chA = 1; chB = 7; chC = -1; }
    else                 { chA = 3; chB = 4; chC = 5;  }

    float a0 = 0.f, a1 = 0.f, a2 = 0.f;

    for (int m = 0; m < 96; ++m) {
        const int r = z + 4 * m;         // <= 383
        const unsigned pk = spk2[2 * m];
        const int plo = pk & 1023, phi = (pk >> 10) & 1023;
        int klo = (plo - 1) >> 2; if (klo < 0) klo = 0;
        int khi = (phi - 1) >> 2; if (khi > 95) khi = 95;
        int nq  = khi - klo + 1;  if (nq < 0) nq = 0;
        const bool bit = (r < IMG - 1) && ((spk2[2 * m + 1] & 1023u) == 0u);
        const bool extra = bit && !(nq > 0 && klo <= 95 && 95 <= khi);
        const int tot = nq + (extra ? 1 : 0);
        for (int e = tid; e < tot; e += THREADS) {
            const int kk = (e < nq) ? (klo + e) : 95;
            const int g  = 96 * r + kk;
            if (g == NGRP - 1) continue; // leftover handled below
            const int pb = 4 * g + 1;
            float mm[4];
            #pragma unroll
            for (int k2 = 0; k2 < 4; ++k2) {
                const int p = pb + k2;
                const int i = p / IMG;
                const int j = p - i * IMG;
                const float X = (float)j * 0.2f - 38.4f;
                const float Y = (float)i * 0.2f - 38.4f;
                const float relx = X - x0, rely = Y - y0;
                const float ax = c * relx + s * rely;
                const float ay = c * rely - s * relx;
                float mv;
                if (plane == 0)
                    mv = (fabsf(ax) <= 5.05f && ay >= 0.f && ay <= dy) ? 1.f : 0.f;
                else if (plane == 1)
                    mv = (fabsf(ax) <= 1.155f && fabsf(ay) <= 2.695f) ? 1.f : 0.f;
                else {
                    const float axl = ax - ox, ayl = ay + oy;
                    mv = (fabsf(axl) <= 3.1f && ayl >= 0.f && ayl <= dyl) ? 1.f : 0.f;
                }
                mm[k2] = mv;
                if (mv > 0.f) {
                    a0 += (bp[chA * NPIX + p] > 0.5f) ? 1.f : 0.f;
                    a1 += (bp[chB * NPIX + p] > 0.5f) ? 1.f : 0.f;
                    if (chC >= 0) a2 += (bp[chC * NPIX + p] > 0.5f) ? 1.f : 0.f;
                }
            }
            v4f v = {mm[0], mm[1], mm[2], mm[3]};
            *(v4f*)(op + pb) = v;
        }
    }

    // block reduction of 3 accumulators
    float acc[3] = {a0, a1, a2};
    #pragma unroll
    for (int k = 0; k < 3; ++k) {
        #pragma unroll
        for (int off = 32; off > 0; off >>= 1)
            acc[k] += __shfl_down(acc[k], off, 64);
    }
    __shared__ float red[4][3];
    const int wid = tid >> 6, lane = tid & 63;
    if (lane == 0) {
        #pragma unroll
        for (int k = 0; k < 3; ++k) red[wid][k] = acc[k];
    }
    __syncthreads();
    if (tid < 3) {
        const float v = red[0][tid] + red[1][tid] + red[2][tid] + red[3][tid];
        int slot = -1;
        if (plane == 0)      slot = (tid == 0) ? 1 : (tid == 1) ? 5 : -1;
        else if (plane == 1) slot = (tid == 0) ? 0 : (tid == 1) ? 6 : -1;
        else                 slot = 2 + tid;
        if (slot >= 0 && v != 0.f) {
            float decay = 1.f;
            for (int qd = 0; qd < t; ++qd) decay *= 0.97f;
            atomicAdd(&out[slot], v * decay);
        }
    }

    // leftover pixels {0, NPIX-3, NPIX-2, NPIX-1}: masks (3 planes) + sums
    if (plane == 0 && z == 0 && tid == 0) {
        float decay = 1.f;
        for (int qd = 0; qd < t; ++qd) decay *= 0.97f;
        const int pp[4] = {0, NPIX - 3, NPIX - 2, NPIX - 1};
        for (int e = 0; e < 4; ++e) {
            const int p = pp[e];
            const int i = p / IMG, j = p - i * IMG;
            const float X = (float)j * 0.2f - 38.4f;
            const float Y = (float)i * 0.2f - 38.4f;
            const float relx = X - x0, rely = Y - y0;
            const float ax = c * relx + s * rely;
            const float ay = c * rely - s * relx;
            const float axl = ax - ox, ayl = ay + oy;
            const float mc  = (fabsf(ax) <= 5.05f  && ay >= 0.f && ay <= dy)   ? 1.f : 0.f;
            const float msd = (fabsf(ax) <= 1.155f && fabsf(ay) <= 2.695f)     ? 1.f : 0.f;
            const float mlt = (fabsf(axl) <= 3.1f  && ayl >= 0.f && ayl <= dyl)? 1.f : 0.f;
            out[7 + (size_t)img * NPIX + p]             = mc;
            out[7 + (size_t)img * NPIX + NMASK + p]     = msd;
            out[7 + (size_t)img * NPIX + 2 * NMASK + p] = mlt;
            if (msd > 0.f) { if (bp[1 * NPIX + p] > 0.5f) atomicAdd(&out[0], decay);
                             if (bp[7 * NPIX + p] > 0.5f) atomicAdd(&out[6], decay); }
            if (mc  > 0.f) { if (bp[2 * NPIX + p] > 0.5f) atomicAdd(&out[1], decay);
                             if (bp[6 * NPIX + p] > 0.5f) atomicAdd(&out[5], decay); }
            if (mlt > 0.f) { if (bp[3 * NPIX + p] > 0.5f) atomicAdd(&out[2], decay);
                             if (bp[4 * NPIX + p] > 0.5f) atomicAdd(&out[3], decay);
                             if (bp[5 * NPIX + p] > 0.5f) atomicAdd(&out[4], decay); }
        }
    }
}

extern "C" void kernel_launch(void* const* d_in, const int* in_sizes, int n_in,
                              void* d_out, int out_size, void* d_ws, size_t ws_size,
                              hipStream_t stream) {
    const float* loc   = (const float*)d_in[0];
    const float* yaw   = (const float*)d_in[1];
    const float* speed = (const float*)d_in[2];
    const float* bev   = (const float*)d_in[3];
    float* out = (float*)d_out;

    // zero the 7 scalar cost slots (atomics accumulate into them)
    (void)hipMemsetAsync(d_out, 0, 7 * sizeof(float), stream);

    dim3 grid(NBX + NSUM, NIMG);
    cost_main<<<grid, THREADS, 0, stream>>>(loc, yaw, speed, bev, out);
}

// Round 9
// 42.773 us; speedup vs baseline: 2.5045x; 2.5045x over previous
//
#include <hip/hip_runtime.h>
#include <math.h>

// Problem constants
constexpr int IMG     = 384;
constexpr int NPIX    = IMG * IMG;        // 147456
constexpr int TM1     = 10;               // T-1
constexpr int NIMG    = 80;               // B * (T-1)
constexpr int THREADS = 256;
constexpr long long NMASK = (long long)NIMG * NPIX;  // 11,796,480

// Output layout: [0..6] = 7 scalar costs, then mask_car, mask_side, mask_light
// Strategy: hipMemsetAsync zeroes the WHOLE output at fill rate (~6.9 TB/s);
// this kernel writes only the rotated-rect interiors + does the gated sums.

__global__ __launch_bounds__(THREADS) void cost_regions(
    const float* __restrict__ loc,    // (8,11,2)
    const float* __restrict__ yaw,    // (8,11,1)
    const float* __restrict__ speed,  // (8,11,1)
    const float* __restrict__ bev,    // (8,11,8,384,384)
    float* __restrict__ out)
{
    const int img = blockIdx.x;          // 0..79
    const int reg = blockIdx.y;          // 0=car, 1=side, 2=light
    const int z   = blockIdx.z;          // stripe 0..3
    const int b   = img / TM1;
    const int t   = img - b * TM1;
    const int tid = threadIdx.x;

    // ---- per-image scalars (bit-identical to rounds 3-7) ----
    const float yaw0 = yaw[b * 11];
    const float c0 = cosf(yaw0), s0 = sinf(yaw0);
    const float rx = loc[(b * 11 + t + 1) * 2 + 0] - loc[b * 22 + 0];
    const float ry = loc[(b * 11 + t + 1) * 2 + 1] - loc[b * 22 + 1];
    const float x0 =  c0 * rx + s0 * ry;
    const float y0 = -s0 * rx + c0 * ry;
    const float yw = yaw[b * 11 + t + 1] - yaw0;
    const float c = cosf(yw), s = sinf(yw);
    const float sp  = speed[b * 11 + t + 1];
    const float dy  = 1.5f * (fmaxf(10.0f, sp) + 4.9f) + 1.0f;
    const float dyl = sp * 0.5f + 14.7f;
    const float ox  = 12.0f * c + 3.25f * s;
    const float oy  = 12.0f * s - 3.25f * c;

    const float* bp = bev + (size_t)((b * 11 + t + 1) * 8) * NPIX;
    float* op = out + 7 + (size_t)img * NPIX + (size_t)reg * NMASK;

    // region rect in aligned (ax, ay) coords
    float u0, u1, v0, v1;
    if (reg == 0)      { u0 = -5.05f;      u1 = 5.05f;      v0 = 0.f;      v1 = dy; }
    else if (reg == 1) { u0 = -1.155f;     u1 = 1.155f;     v0 = -2.695f;  v1 = 2.695f; }
    else               { u0 = ox - 3.1f;   u1 = ox + 3.1f;  v0 = -oy;      v1 = dyl - oy; }

    // conservative bbox in (X, Y) via inverse rotation of the 4 corners
    float Xmn = 1e30f, Xmx = -1e30f, Ymn = 1e30f, Ymx = -1e30f;
    #pragma unroll
    for (int cu = 0; cu < 2; ++cu)
        #pragma unroll
        for (int cv = 0; cv < 2; ++cv) {
            const float u = cu ? u1 : u0, v = cv ? v1 : v0;
            const float X = x0 + c * u - s * v;
            const float Y = y0 + s * u + c * v;
            Xmn = fminf(Xmn, X); Xmx = fmaxf(Xmx, X);
            Ymn = fminf(Ymn, Y); Ymx = fmaxf(Ymx, Y);
        }
    const int j0 = max(0, (int)floorf((Xmn + 38.4f) * 5.f) - 1);
    const int j1 = min(IMG - 1, (int)ceilf((Xmx + 38.4f) * 5.f) + 1);
    const int i0 = max(0, (int)floorf((Ymn + 38.4f) * 5.f) - 1);
    const int i1 = min(IMG - 1, (int)ceilf((Ymx + 38.4f) * 5.f) + 1);

    float a0 = 0.f, a1 = 0.f, a2 = 0.f;

    if (j1 >= j0 && i1 >= i0) {
        const int w = j1 - j0 + 1;
        const int n = w * (i1 - i0 + 1);
        for (int idx = tid + z * THREADS; idx < n; idx += 4 * THREADS) {
            const int ii = idx / w;
            const int jj = j0 + (idx - ii * w);
            const int i  = i0 + ii;
            const float X = (float)jj * 0.2f - 38.4f;
            const float Y = (float)i  * 0.2f - 38.4f;
            const float relx = X - x0, rely = Y - y0;
            const float ax = c * relx + s * rely;
            const float ay = c * rely - s * relx;
            const int p = i * IMG + jj;
            if (reg == 0) {
                if (fabsf(ax) <= 5.05f && ay >= 0.f && ay <= dy) {
                    op[p] = 1.0f;
                    a0 += (bp[2 * NPIX + p] > 0.5f) ? 1.f : 0.f;   // vehicle
                    a1 += (bp[6 * NPIX + p] > 0.5f) ? 1.f : 0.f;   // pedestrian
                }
            } else if (reg == 1) {
                if (fabsf(ax) <= 1.155f && fabsf(ay) <= 2.695f) {
                    op[p] = 1.0f;
                    a0 += (bp[1 * NPIX + p] > 0.5f) ? 1.f : 0.f;   // lane
                    a1 += (bp[7 * NPIX + p] > 0.5f) ? 1.f : 0.f;   // offroad
                }
            } else {
                const float axl = ax - ox, ayl = ay + oy;
                if (fabsf(axl) <= 3.1f && ayl >= 0.f && ayl <= dyl) {
                    op[p] = 1.0f;
                    a0 += (bp[3 * NPIX + p] > 0.5f) ? 1.f : 0.f;   // green
                    a1 += (bp[4 * NPIX + p] > 0.5f) ? 1.f : 0.f;   // yellow
                    a2 += (bp[5 * NPIX + p] > 0.5f) ? 1.f : 0.f;   // red
                }
            }
        }
    }

    // block reduction of 3 accumulators
    float acc[3] = {a0, a1, a2};
    #pragma unroll
    for (int k = 0; k < 3; ++k) {
        #pragma unroll
        for (int off = 32; off > 0; off >>= 1)
            acc[k] += __shfl_down(acc[k], off, 64);
    }
    __shared__ float red[4][3];
    const int wid = tid >> 6, lane = tid & 63;
    if (lane == 0) {
        #pragma unroll
        for (int k = 0; k < 3; ++k) red[wid][k] = acc[k];
    }
    __syncthreads();
    if (tid < 3) {
        const float v = red[0][tid] + red[1][tid] + red[2][tid] + red[3][tid];
        if (v != 0.0f) {
            float decay = 1.0f;
            for (int qd = 0; qd < t; ++qd) decay *= 0.97f;
            // slots: lane=0, vehicle=1, green=2, yellow=3, red=4, ped=5, offroad=6
            int slot;
            if (reg == 0)      slot = (tid == 0) ? 1 : 5;      // vehicle, pedestrian
            else if (reg == 1) slot = (tid == 0) ? 0 : 6;      // lane, offroad
            else               slot = 2 + tid;                 // green, yellow, red
            if (reg == 2 || tid < 2)
                atomicAdd(&out[slot], v * decay);
        }
    }
}

extern "C" void kernel_launch(void* const* d_in, const int* in_sizes, int n_in,
                              void* d_out, int out_size, void* d_ws, size_t ws_size,
                              hipStream_t stream) {
    const float* loc   = (const float*)d_in[0];
    const float* yaw   = (const float*)d_in[1];
    const float* speed = (const float*)d_in[2];
    const float* bev   = (const float*)d_in[3];
    float* out = (float*)d_out;

    // Zero the ENTIRE output (7 cost slots + all three mask planes) at the
    // device fill rate (~6.9 TB/s demonstrated). The region kernel then only
    // writes rectangle interiors.
    (void)hipMemsetAsync(d_out, 0, (size_t)out_size * sizeof(float), stream);

    dim3 grid(NIMG, 3, 4);
    cost_regions<<<grid, THREADS, 0, stream>>>(loc, yaw, speed, bev, out);
}

// Round 10
// 37.119 us; speedup vs baseline: 2.8860x; 1.1523x over previous
//
#include <hip/hip_runtime.h>
#include <math.h>

// Problem constants
constexpr int IMG     = 384;
constexpr int NPIX    = IMG * IMG;        // 147456
constexpr int TM1     = 10;               // T-1
constexpr int NIMG    = 80;               // B * (T-1)
constexpr int THREADS = 256;
constexpr int GPT     = 4;                // quads per thread per unit
constexpr int GPB     = THREADS * GPT;    // 1024 quads per unit (48 KB/plane)
constexpr int NGRP    = NPIX / 4;         // 36864 quad slots per image-plane
constexpr int CHUNKS  = NGRP / GPB;       // 36 units per image
constexpr int NUNITS  = NIMG * CHUNKS;    // 2880 streamer units
constexpr int UPB     = 4;                // units per streamer block
constexpr int NSTRB   = NUNITS / UPB;     // 720 streamer blocks
constexpr int NSUMB   = NIMG * 12;        // 960 sum blocks (3 regions x 4 stripes)
constexpr long long NMASK = (long long)NIMG * NPIX;  // 11,796,480

typedef float v4f __attribute__((ext_vector_type(4)));

// Output layout: [0..6] = 7 scalar costs, then mask_car, mask_side, mask_light

__global__ __launch_bounds__(THREADS) void cost_main(
    const float* __restrict__ loc,    // (8,11,2)
    const float* __restrict__ yaw,    // (8,11,1)
    const float* __restrict__ speed,  // (8,11,1)
    const float* __restrict__ bev,    // (8,11,8,384,384)
    float* __restrict__ out)
{
    const int tid = threadIdx.x;

    if (blockIdx.x < NSUMB) {
        // ============== sum path: bbox walk + gated loads ===================
        const int img = blockIdx.x / 12;
        const int q   = blockIdx.x - img * 12;
        const int reg = q >> 2;              // 0=car, 1=side, 2=light
        const int z   = q & 3;               // stripe 0..3
        const int b   = img / TM1;
        const int t   = img - b * TM1;

        const float yaw0 = yaw[b * 11];
        const float c0 = cosf(yaw0), s0 = sinf(yaw0);
        const float rx = loc[(b * 11 + t + 1) * 2 + 0] - loc[b * 22 + 0];
        const float ry = loc[(b * 11 + t + 1) * 2 + 1] - loc[b * 22 + 1];
        const float x0 =  c0 * rx + s0 * ry;
        const float y0 = -s0 * rx + c0 * ry;
        const float yw = yaw[b * 11 + t + 1] - yaw0;
        const float c = cosf(yw), s = sinf(yw);
        const float sp  = speed[b * 11 + t + 1];
        const float dy  = 1.5f * (fmaxf(10.0f, sp) + 4.9f) + 1.0f;
        const float dyl = sp * 0.5f + 14.7f;
        const float ox  = 12.0f * c + 3.25f * s;
        const float oy  = 12.0f * s - 3.25f * c;

        const float* bp = bev + (size_t)((b * 11 + t + 1) * 8) * NPIX;

        float u0, u1, v0, v1;
        if (reg == 0)      { u0 = -5.05f;      u1 = 5.05f;      v0 = 0.f;      v1 = dy; }
        else if (reg == 1) { u0 = -1.155f;     u1 = 1.155f;     v0 = -2.695f;  v1 = 2.695f; }
        else               { u0 = ox - 3.1f;   u1 = ox + 3.1f;  v0 = -oy;      v1 = dyl - oy; }

        float Xmn = 1e30f, Xmx = -1e30f, Ymn = 1e30f, Ymx = -1e30f;
        #pragma unroll
        for (int cu = 0; cu < 2; ++cu)
            #pragma unroll
            for (int cv = 0; cv < 2; ++cv) {
                const float u = cu ? u1 : u0, v = cv ? v1 : v0;
                const float X = x0 + c * u - s * v;
                const float Y = y0 + s * u + c * v;
                Xmn = fminf(Xmn, X); Xmx = fmaxf(Xmx, X);
                Ymn = fminf(Ymn, Y); Ymx = fmaxf(Ymx, Y);
            }
        const int j0 = max(0, (int)floorf((Xmn + 38.4f) * 5.f) - 1);
        const int j1 = min(IMG - 1, (int)ceilf((Xmx + 38.4f) * 5.f) + 1);
        const int i0 = max(0, (int)floorf((Ymn + 38.4f) * 5.f) - 1);
        const int i1 = min(IMG - 1, (int)ceilf((Ymx + 38.4f) * 5.f) + 1);

        float a0 = 0.f, a1 = 0.f, a2 = 0.f;

        if (j1 >= j0 && i1 >= i0) {
            const int w = j1 - j0 + 1;
            const int n = w * (i1 - i0 + 1);
            for (int idx = tid + z * THREADS; idx < n; idx += 4 * THREADS) {
                const int ii = idx / w;
                const int jj = j0 + (idx - ii * w);
                const int i  = i0 + ii;
                const float X = (float)jj * 0.2f - 38.4f;
                const float Y = (float)i  * 0.2f - 38.4f;
                const float relx = X - x0, rely = Y - y0;
                const float ax = c * relx + s * rely;
                const float ay = c * rely - s * relx;
                const int p = i * IMG + jj;
                if (reg == 0) {
                    if (fabsf(ax) <= 5.05f && ay >= 0.f && ay <= dy) {
                        a0 += (bp[2 * NPIX + p] > 0.5f) ? 1.f : 0.f;   // vehicle
                        a1 += (bp[6 * NPIX + p] > 0.5f) ? 1.f : 0.f;   // pedestrian
                    }
                } else if (reg == 1) {
                    if (fabsf(ax) <= 1.155f && fabsf(ay) <= 2.695f) {
                        a0 += (bp[1 * NPIX + p] > 0.5f) ? 1.f : 0.f;   // lane
                        a1 += (bp[7 * NPIX + p] > 0.5f) ? 1.f : 0.f;   // offroad
                    }
                } else {
                    const float axl = ax - ox, ayl = ay + oy;
                    if (fabsf(axl) <= 3.1f && ayl >= 0.f && ayl <= dyl) {
                        a0 += (bp[3 * NPIX + p] > 0.5f) ? 1.f : 0.f;   // green
                        a1 += (bp[4 * NPIX + p] > 0.5f) ? 1.f : 0.f;   // yellow
                        a2 += (bp[5 * NPIX + p] > 0.5f) ? 1.f : 0.f;   // red
                    }
                }
            }
        }

        float acc[3] = {a0, a1, a2};
        #pragma unroll
        for (int k = 0; k < 3; ++k) {
            #pragma unroll
            for (int off = 32; off > 0; off >>= 1)
                acc[k] += __shfl_down(acc[k], off, 64);
        }
        __shared__ float red[4][3];
        const int wid = tid >> 6, lane = tid & 63;
        if (lane == 0) {
            #pragma unroll
            for (int k = 0; k < 3; ++k) red[wid][k] = acc[k];
        }
        __syncthreads();
        if (tid < 3) {
            const float v = red[0][tid] + red[1][tid] + red[2][tid] + red[3][tid];
            if (v != 0.0f) {
                float decay = 1.0f;
                for (int qd = 0; qd < t; ++qd) decay *= 0.97f;
                // slots: lane=0, vehicle=1, green=2, yellow=3, red=4, ped=5, offroad=6
                int slot;
                if (reg == 0)      slot = (tid == 0) ? 1 : 5;
                else if (reg == 1) slot = (tid == 0) ? 0 : 6;
                else               slot = 2 + tid;
                if (reg == 2 || tid < 2)
                    atomicAdd(&out[slot], v * decay);
            }
        }
        return;
    }

    // ============== streamer path: persistent blocks, grid-stride units =====
    const int sid = blockIdx.x - NSUMB;      // 0..719
    #pragma unroll
    for (int uu = 0; uu < UPB; ++uu) {
        const int u     = sid * UPB + uu;    // 0..2879 (4 consecutive chunks)
        const int img   = u / CHUNKS;
        const int chunk = u - img * CHUNKS;
        const int b     = img / TM1;
        const int t     = img - b * TM1;

        const float yaw0 = yaw[b * 11];
        const float c0 = cosf(yaw0), s0 = sinf(yaw0);
        const float rx = loc[(b * 11 + t + 1) * 2 + 0] - loc[b * 22 + 0];
        const float ry = loc[(b * 11 + t + 1) * 2 + 1] - loc[b * 22 + 1];
        const float x0 =  c0 * rx + s0 * ry;
        const float y0 = -s0 * rx + c0 * ry;
        const float yw = yaw[b * 11 + t + 1] - yaw0;
        const float c = cosf(yw), s = sinf(yw);
        const float sp  = speed[b * 11 + t + 1];
        const float dy  = 1.5f * (fmaxf(10.0f, sp) + 4.9f) + 1.0f;
        const float dyl = sp * 0.5f + 14.7f;
        const float ox  = 12.0f * c + 3.25f * s;
        const float oy  = 12.0f * s - 3.25f * c;

        float* ocar   = out + 7 + (size_t)img * NPIX;
        float* oside  = ocar + NMASK;
        float* olight = ocar + 2 * NMASK;

        const int g0 = chunk * GPB + tid;
        #pragma unroll
        for (int it = 0; it < GPT; ++it) {
            const int g = g0 + it * THREADS;
            if (g != NGRP - 1) {
                const int pb = 4 * g + 1;    // pixels pb..pb+3, 16B-aligned
                float mc[4], ms[4], ml[4];
                #pragma unroll
                for (int k = 0; k < 4; ++k) {
                    const int p = pb + k;
                    const int i = p / IMG;
                    const int j = p - i * IMG;
                    const float X = (float)j * 0.2f - 38.4f;
                    const float Y = (float)i * 0.2f - 38.4f;
                    const float relx = X - x0, rely = Y - y0;
                    const float ax = c * relx + s * rely;
                    const float ay = c * rely - s * relx;
                    const float axl = ax - ox, ayl = ay + oy;
                    mc[k] = (fabsf(ax)  <= 5.05f  && ay >= 0.f && ay <= dy)   ? 1.f : 0.f;
                    ms[k] = (fabsf(ax)  <= 1.155f && fabsf(ay) <= 2.695f)     ? 1.f : 0.f;
                    ml[k] = (fabsf(axl) <= 3.1f   && ayl >= 0.f && ayl <= dyl)? 1.f : 0.f;
                }
                v4f vc = {mc[0], mc[1], mc[2], mc[3]};
                v4f vs = {ms[0], ms[1], ms[2], ms[3]};
                v4f vl = {ml[0], ml[1], ml[2], ml[3]};
                *(v4f*)(ocar + pb)   = vc;
                *(v4f*)(oside + pb)  = vs;
                *(v4f*)(olight + pb) = vl;
            } else {
                // leftover pixels {0, NPIX-3, NPIX-2, NPIX-1} for this image
                const int pp[4] = {0, NPIX - 3, NPIX - 2, NPIX - 1};
                for (int k = 0; k < 4; ++k) {
                    const int p = pp[k];
                    const int i = p / IMG;
                    const int j = p - i * IMG;
                    const float X = (float)j * 0.2f - 38.4f;
                    const float Y = (float)i * 0.2f - 38.4f;
                    const float relx = X - x0, rely = Y - y0;
                    const float ax = c * relx + s * rely;
                    const float ay = c * rely - s * relx;
                    const float axl = ax - ox, ayl = ay + oy;
                    ocar[p]   = (fabsf(ax)  <= 5.05f  && ay >= 0.f && ay <= dy)    ? 1.f : 0.f;
                    oside[p]  = (fabsf(ax)  <= 1.155f && fabsf(ay) <= 2.695f)      ? 1.f : 0.f;
                    olight[p] = (fabsf(axl) <= 3.1f   && ayl >= 0.f && ayl <= dyl) ? 1.f : 0.f;
                }
            }
        }
    }
}

extern "C" void kernel_launch(void* const* d_in, const int* in_sizes, int n_in,
                              void* d_out, int out_size, void* d_ws, size_t ws_size,
                              hipStream_t stream) {
    const float* loc   = (const float*)d_in[0];
    const float* yaw   = (const float*)d_in[1];
    const float* speed = (const float*)d_in[2];
    const float* bev   = (const float*)d_in[3];
    float* out = (float*)d_out;

    // zero the 7 scalar cost slots (atomics accumulate into them)
    (void)hipMemsetAsync(d_out, 0, 7 * sizeof(float), stream);

    dim3 grid(NSUMB + NSTRB, 1);
    cost_main<<<grid, THREADS, 0, stream>>>(loc, yaw, speed, bev, out);
}

// Round 11
// 35.497 us; speedup vs baseline: 3.0179x; 1.0457x over previous
//
#include <hip/hip_runtime.h>
#include <math.h>

// Problem constants
constexpr int IMG     = 384;
constexpr int NPIX    = IMG * IMG;        // 147456
constexpr int TM1     = 10;               // T-1
constexpr int NIMG    = 80;               // B * (T-1)
constexpr int THREADS = 256;
constexpr int GPT     = 4;                // quads per thread per unit
constexpr int GPB     = THREADS * GPT;    // 1024 quads per unit (48 KB/plane)
constexpr int NGRP    = NPIX / 4;         // 36864 quad slots per image-plane
constexpr int CHUNKS  = NGRP / GPB;       // 36 units per image
constexpr int NUNITS  = NIMG * CHUNKS;    // 2880 streamer units
constexpr int UPB     = 4;                // units per streamer block
constexpr int NSTRB   = NUNITS / UPB;     // 720 streamer blocks
constexpr int NSUMB   = NIMG * 12;        // 960 sum blocks (3 regions x 4 stripes)
constexpr long long NMASK = (long long)NIMG * NPIX;  // 11,796,480

typedef float v4f __attribute__((ext_vector_type(4)));

// Output layout: [0..6] = 7 scalar costs, then mask_car, mask_side, mask_light

__global__ __launch_bounds__(THREADS) void cost_main(
    const float* __restrict__ loc,    // (8,11,2)
    const float* __restrict__ yaw,    // (8,11,1)
    const float* __restrict__ speed,  // (8,11,1)
    const float* __restrict__ bev,    // (8,11,8,384,384)
    float* __restrict__ out)
{
    const int tid = threadIdx.x;

    if (blockIdx.x < NSUMB) {
        // ============== sum path: bbox walk + gated loads (r10 verbatim) ====
        const int img = blockIdx.x / 12;
        const int q   = blockIdx.x - img * 12;
        const int reg = q >> 2;              // 0=car, 1=side, 2=light
        const int z   = q & 3;               // stripe 0..3
        const int b   = img / TM1;
        const int t   = img - b * TM1;

        const float yaw0 = yaw[b * 11];
        const float c0 = cosf(yaw0), s0 = sinf(yaw0);
        const float rx = loc[(b * 11 + t + 1) * 2 + 0] - loc[b * 22 + 0];
        const float ry = loc[(b * 11 + t + 1) * 2 + 1] - loc[b * 22 + 1];
        const float x0 =  c0 * rx + s0 * ry;
        const float y0 = -s0 * rx + c0 * ry;
        const float yw = yaw[b * 11 + t + 1] - yaw0;
        const float c = cosf(yw), s = sinf(yw);
        const float sp  = speed[b * 11 + t + 1];
        const float dy  = 1.5f * (fmaxf(10.0f, sp) + 4.9f) + 1.0f;
        const float dyl = sp * 0.5f + 14.7f;
        const float ox  = 12.0f * c + 3.25f * s;
        const float oy  = 12.0f * s - 3.25f * c;

        const float* bp = bev + (size_t)((b * 11 + t + 1) * 8) * NPIX;

        float u0, u1, v0, v1;
        if (reg == 0)      { u0 = -5.05f;      u1 = 5.05f;      v0 = 0.f;      v1 = dy; }
        else if (reg == 1) { u0 = -1.155f;     u1 = 1.155f;     v0 = -2.695f;  v1 = 2.695f; }
        else               { u0 = ox - 3.1f;   u1 = ox + 3.1f;  v0 = -oy;      v1 = dyl - oy; }

        float Xmn = 1e30f, Xmx = -1e30f, Ymn = 1e30f, Ymx = -1e30f;
        #pragma unroll
        for (int cu = 0; cu < 2; ++cu)
            #pragma unroll
            for (int cv = 0; cv < 2; ++cv) {
                const float u = cu ? u1 : u0, v = cv ? v1 : v0;
                const float X = x0 + c * u - s * v;
                const float Y = y0 + s * u + c * v;
                Xmn = fminf(Xmn, X); Xmx = fmaxf(Xmx, X);
                Ymn = fminf(Ymn, Y); Ymx = fmaxf(Ymx, Y);
            }
        const int j0 = max(0, (int)floorf((Xmn + 38.4f) * 5.f) - 1);
        const int j1 = min(IMG - 1, (int)ceilf((Xmx + 38.4f) * 5.f) + 1);
        const int i0 = max(0, (int)floorf((Ymn + 38.4f) * 5.f) - 1);
        const int i1 = min(IMG - 1, (int)ceilf((Ymx + 38.4f) * 5.f) + 1);

        float a0 = 0.f, a1 = 0.f, a2 = 0.f;

        if (j1 >= j0 && i1 >= i0) {
            const int w = j1 - j0 + 1;
            const int n = w * (i1 - i0 + 1);
            for (int idx = tid + z * THREADS; idx < n; idx += 4 * THREADS) {
                const int ii = idx / w;
                const int jj = j0 + (idx - ii * w);
                const int i  = i0 + ii;
                const float X = (float)jj * 0.2f - 38.4f;
                const float Y = (float)i  * 0.2f - 38.4f;
                const float relx = X - x0, rely = Y - y0;
                const float ax = c * relx + s * rely;
                const float ay = c * rely - s * relx;
                const int p = i * IMG + jj;
                if (reg == 0) {
                    if (fabsf(ax) <= 5.05f && ay >= 0.f && ay <= dy) {
                        a0 += (bp[2 * NPIX + p] > 0.5f) ? 1.f : 0.f;   // vehicle
                        a1 += (bp[6 * NPIX + p] > 0.5f) ? 1.f : 0.f;   // pedestrian
                    }
                } else if (reg == 1) {
                    if (fabsf(ax) <= 1.155f && fabsf(ay) <= 2.695f) {
                        a0 += (bp[1 * NPIX + p] > 0.5f) ? 1.f : 0.f;   // lane
                        a1 += (bp[7 * NPIX + p] > 0.5f) ? 1.f : 0.f;   // offroad
                    }
                } else {
                    const float axl = ax - ox, ayl = ay + oy;
                    if (fabsf(axl) <= 3.1f && ayl >= 0.f && ayl <= dyl) {
                        a0 += (bp[3 * NPIX + p] > 0.5f) ? 1.f : 0.f;   // green
                        a1 += (bp[4 * NPIX + p] > 0.5f) ? 1.f : 0.f;   // yellow
                        a2 += (bp[5 * NPIX + p] > 0.5f) ? 1.f : 0.f;   // red
                    }
                }
            }
        }

        float acc[3] = {a0, a1, a2};
        #pragma unroll
        for (int k = 0; k < 3; ++k) {
            #pragma unroll
            for (int off = 32; off > 0; off >>= 1)
                acc[k] += __shfl_down(acc[k], off, 64);
        }
        __shared__ float red[4][3];
        const int wid = tid >> 6, lane = tid & 63;
        if (lane == 0) {
            #pragma unroll
            for (int k = 0; k < 3; ++k) red[wid][k] = acc[k];
        }
        __syncthreads();
        if (tid < 3) {
            const float v = red[0][tid] + red[1][tid] + red[2][tid] + red[3][tid];
            if (v != 0.0f) {
                float decay = 1.0f;
                for (int qd = 0; qd < t; ++qd) decay *= 0.97f;
                // slots: lane=0, vehicle=1, green=2, yellow=3, red=4, ped=5, offroad=6
                int slot;
                if (reg == 0)      slot = (tid == 0) ? 1 : 5;
                else if (reg == 1) slot = (tid == 0) ? 0 : 6;
                else               slot = 2 + tid;
                if (reg == 2 || tid < 2)
                    atomicAdd(&out[slot], v * decay);
            }
        }
        return;
    }

    // ============== streamer path: persistent blocks, low-VALU inner ========
    const int sid = blockIdx.x - NSUMB;      // 0..719
    #pragma unroll
    for (int uu = 0; uu < UPB; ++uu) {
        const int u     = sid * UPB + uu;    // 0..2879 (4 consecutive chunks)
        const int img   = u / CHUNKS;
        const int chunk = u - img * CHUNKS;
        const int b     = img / TM1;
        const int t     = img - b * TM1;

        const float yaw0 = yaw[b * 11];
        const float c0 = cosf(yaw0), s0 = sinf(yaw0);
        const float rx = loc[(b * 11 + t + 1) * 2 + 0] - loc[b * 22 + 0];
        const float ry = loc[(b * 11 + t + 1) * 2 + 1] - loc[b * 22 + 1];
        const float x0 =  c0 * rx + s0 * ry;
        const float y0 = -s0 * rx + c0 * ry;
        const float yw = yaw[b * 11 + t + 1] - yaw0;
        const float c = cosf(yw), s = sinf(yw);
        const float sp  = speed[b * 11 + t + 1];
        const float dy  = 1.5f * (fmaxf(10.0f, sp) + 4.9f) + 1.0f;
        const float dyl = sp * 0.5f + 14.7f;
        const float ox  = 12.0f * c + 3.25f * s;
        const float oy  = 12.0f * s - 3.25f * c;

        // affine mask coords: ax = Axj*j + Axi*i + Cx ; ay = Ayj*j + Ayi*i + Cy
        const float Axj = 0.2f * c,  Axi = 0.2f * s;
        const float Ayj = -0.2f * s, Ayi = 0.2f * c;
        const float Cx  = c * (-38.4f - x0) + s * (-38.4f - y0);
        const float Cy  = c * (-38.4f - y0) + s * (38.4f + x0);

        float* ocar   = out + 7 + (size_t)img * NPIX;
        float* oside  = ocar + NMASK;
        float* olight = ocar + 2 * NMASK;

        const int g0 = chunk * GPB + tid;
        #pragma unroll
        for (int it = 0; it < GPT; ++it) {
            const int g = g0 + it * THREADS;
            if (g != NGRP - 1) {
                const int pb = 4 * g + 1;        // pixels pb..pb+3, 16B-aligned
                const int i0r = pb / IMG;        // one div per quad
                const int c1  = pb - i0r * IMG;  // col of first pixel (1..381, ≡1 mod 4)
                const float fi  = (float)i0r;
                const float fj0 = (float)c1;
                float ax = fmaf(Axj, fj0, fmaf(Axi, fi, Cx));
                float ay = fmaf(Ayj, fj0, fmaf(Ayi, fi, Cy));
                float mcv[4], msv[4], mlv[4];
                #pragma unroll
                for (int k = 0; k < 4; ++k) {
                    float axk = ax, ayk = ay;
                    if (k == 3 && c1 == 381) {   // wrap pixel -> (i+1, j=0)
                        axk = fmaf(Axi, fi + 1.f, Cx);
                        ayk = fmaf(Ayi, fi + 1.f, Cy);
                    }
                    const float axl = axk - ox, ayl = ayk + oy;
                    mcv[k] = (fminf(fminf(5.05f - fabsf(axk), ayk), dy - ayk) >= 0.f) ? 1.f : 0.f;
                    msv[k] = (fminf(1.155f - fabsf(axk), 2.695f - fabsf(ayk)) >= 0.f) ? 1.f : 0.f;
                    mlv[k] = (fminf(fminf(3.1f - fabsf(axl), ayl), dyl - ayl) >= 0.f) ? 1.f : 0.f;
                    ax += Axj; ay += Ayj;
                }
                v4f vc = {mcv[0], mcv[1], mcv[2], mcv[3]};
                v4f vs = {msv[0], msv[1], msv[2], msv[3]};
                v4f vl = {mlv[0], mlv[1], mlv[2], mlv[3]};
                *(v4f*)(ocar + pb)   = vc;
                *(v4f*)(oside + pb)  = vs;
                *(v4f*)(olight + pb) = vl;
            } else {
                // leftover pixels {0, NPIX-3, NPIX-2, NPIX-1} (proven r6 path)
                const int pp[4] = {0, NPIX - 3, NPIX - 2, NPIX - 1};
                for (int k = 0; k < 4; ++k) {
                    const int p = pp[k];
                    const int i = p / IMG;
                    const int j = p - i * IMG;
                    const float X = (float)j * 0.2f - 38.4f;
                    const float Y = (float)i * 0.2f - 38.4f;
                    const float relx = X - x0, rely = Y - y0;
                    const float ax2 = c * relx + s * rely;
                    const float ay2 = c * rely - s * relx;
                    const float axl = ax2 - ox, ayl = ay2 + oy;
                    ocar[p]   = (fabsf(ax2) <= 5.05f  && ay2 >= 0.f && ay2 <= dy)   ? 1.f : 0.f;
                    oside[p]  = (fabsf(ax2) <= 1.155f && fabsf(ay2) <= 2.695f)      ? 1.f : 0.f;
                    olight[p] = (fabsf(axl) <= 3.1f   && ayl >= 0.f && ayl <= dyl)  ? 1.f : 0.f;
                }
            }
        }
    }
}

extern "C" void kernel_launch(void* const* d_in, const int* in_sizes, int n_in,
                              void* d_out, int out_size, void* d_ws, size_t ws_size,
                              hipStream_t stream) {
    const float* loc   = (const float*)d_in[0];
    const float* yaw   = (const float*)d_in[1];
    const float* speed = (const float*)d_in[2];
    const float* bev   = (const float*)d_in[3];
    float* out = (float*)d_out;

    // zero the 7 scalar cost slots (atomics accumulate into them)
    (void)hipMemsetAsync(d_out, 0, 7 * sizeof(float), stream);

    dim3 grid(NSUMB + NSTRB, 1);
    cost_main<<<grid, THREADS, 0, stream>>>(loc, yaw, speed, bev, out);
}